// Round 1
// baseline (651.719 us; speedup 1.0000x reference)
//
#include <hip/hip_runtime.h>

// ---------------------------------------------------------------------------
// Problem: B=4, S=4096, D=1024 linear attention (feature map phi = elu+1)
//   q_phi = phi(x Wq + bq); k_phi = phi(c Wk + bk); v = c Wv + bv
//   kv = k_phi^T v (per batch); k_sum = sum_s k_phi
//   z = 1/(q_phi . k_sum + 1e-6); att = (q_phi kv) * z
//   out = att Wo + bo + x
// Strategy: bf16 MFMA GEMMs (m97-style 128x128 tile, global_load_lds w=16),
// all operands K-innermost (BT form); fp32 accumulate; fp32 residual exact.
// ---------------------------------------------------------------------------

typedef __bf16 bf16x8 __attribute__((ext_vector_type(8)));
typedef __bf16 bf16x4 __attribute__((ext_vector_type(4)));
typedef float  f32x4  __attribute__((ext_vector_type(4)));

#define GLOBAL_AS __attribute__((address_space(1)))
#define LDS_AS    __attribute__((address_space(3)))

__device__ __forceinline__ __bf16 f2bf(float f) {
  union { float f; unsigned u; } a; a.f = f;
  unsigned r = a.u + 0x7FFFu + ((a.u >> 16) & 1u);   // RNE (no NaN inputs here)
  union { unsigned short s; __bf16 b; } o; o.s = (unsigned short)(r >> 16);
  return o.b;
}

__device__ __forceinline__ void async_load16(const void* g, void* l) {
  __builtin_amdgcn_global_load_lds((const GLOBAL_AS void*)g, (LDS_AS void*)l, 16, 0, 0);
}

// ---------------------------------------------------------------------------
// GEMM: C[m][n] = sum_k A[m][k] * BT[n][k]   (A: MxK row-major, BT: NxK row-major)
// 128x128 tile, BK=32, 256 threads = 4 waves (2x2), each wave 4x4 16x16x32 MFMAs.
// MODE: 0 = bias+phi->bf16, 1 = bias->bf16, 2 = plain->bf16,
//       3 = *z[row]->bf16,  4 = bias+residual->f32
// ---------------------------------------------------------------------------
template<int MODE>
__global__ __launch_bounds__(256)
void gemm_bt(const __bf16* __restrict__ Ag, const __bf16* __restrict__ Bg,
             void* __restrict__ Cg, int N, int K,
             long sA, long sB, long sC,
             const float* __restrict__ bias,
             const float* __restrict__ zvec, long sZ,
             const float* __restrict__ resid)
{
  __shared__ __bf16 As[128 * 32];
  __shared__ __bf16 Bs[128 * 32];

  const int tid  = threadIdx.x;
  const int bz   = blockIdx.z;
  const __bf16* A = Ag + (long)blockIdx.y * 128 * K + bz * sA;
  const __bf16* B = Bg + (long)blockIdx.x * 128 * K + bz * sB;

  // staging map: thread t covers 8 bf16 = 16B; row = t/4 (+64 for chunk 1), col = (t%4)*8
  const int sr = tid >> 2;
  const int sc = (tid & 3) * 8;

  const int lane = tid & 63;
  const int wave = tid >> 6;
  const int wm   = (wave >> 1) * 64;
  const int wn   = (wave & 1) * 64;
  const int ln   = lane & 15;
  const int quad = lane >> 4;

  f32x4 acc[4][4];
  const f32x4 zero = {0.f, 0.f, 0.f, 0.f};
#pragma unroll
  for (int i = 0; i < 4; i++)
#pragma unroll
    for (int j = 0; j < 4; j++) acc[i][j] = zero;

  for (int k0 = 0; k0 < K; k0 += 32) {
    async_load16(A + (long)sr * K        + k0 + sc, As + tid * 8);
    async_load16(A + (long)(sr + 64) * K + k0 + sc, As + 2048 + tid * 8);
    async_load16(B + (long)sr * K        + k0 + sc, Bs + tid * 8);
    async_load16(B + (long)(sr + 64) * K + k0 + sc, Bs + 2048 + tid * 8);
    __syncthreads();   // compiler drains vmcnt(0) before s_barrier

    bf16x8 af[4], bfr[4];
#pragma unroll
    for (int i = 0; i < 4; i++)
      af[i] = *(const bf16x8*)(As + (wm + i * 16 + ln) * 32 + quad * 8);
#pragma unroll
    for (int j = 0; j < 4; j++)
      bfr[j] = *(const bf16x8*)(Bs + (wn + j * 16 + ln) * 32 + quad * 8);
#pragma unroll
    for (int i = 0; i < 4; i++)
#pragma unroll
      for (int j = 0; j < 4; j++)
        acc[i][j] = __builtin_amdgcn_mfma_f32_16x16x32_bf16(af[i], bfr[j], acc[i][j], 0, 0, 0);
    __syncthreads();
  }

  // epilogue: C/D layout col = lane&15, row = quad*4 + reg (m89-verified)
  const long m0  = (long)blockIdx.y * 128;
  const int  n0g = blockIdx.x * 128;
#pragma unroll
  for (int i = 0; i < 4; i++) {
#pragma unroll
    for (int j = 0; j < 4; j++) {
#pragma unroll
      for (int r = 0; r < 4; r++) {
        const int lrow = wm + i * 16 + quad * 4 + r;
        const int lcol = wn + j * 16 + ln;
        const long gm  = m0 + lrow;
        const int  gn  = n0g + lcol;
        float x = acc[i][j][r];
        if (MODE == 0 || MODE == 1 || MODE == 4) x += bias[gn];
        if (MODE == 0) x = (x > 0.f) ? (x + 1.f) : __expf(x);   // elu(x)+1
        if (MODE == 3) x *= zvec[(long)bz * sZ + gm];
        if (MODE == 4) {
          ((float*)Cg)[gm * (long)N + gn] = x + resid[gm * (long)N + gn];
        } else {
          ((__bf16*)Cg)[(long)bz * sC + gm * (long)N + gn] = f2bf(x);
        }
      }
    }
  }
}

// ---------------------------------------------------------------------------
// fp32 -> bf16 convert (vectorized)
// ---------------------------------------------------------------------------
__global__ __launch_bounds__(256)
void cvt_f32_bf16(const float* __restrict__ x, __bf16* __restrict__ y, long n)
{
  long i = ((long)blockIdx.x * 256 + threadIdx.x) * 4;
  if (i < n) {
    float4 v = *(const float4*)(x + i);
    bf16x4 o;
    o[0] = f2bf(v.x); o[1] = f2bf(v.y); o[2] = f2bf(v.z); o[3] = f2bf(v.w);
    *(bf16x4*)(y + i) = o;
  }
}

// ---------------------------------------------------------------------------
// bf16 [R][Cn] -> [Cn][R] transpose, 64x64 LDS tiles, batched (blockIdx.z)
// ---------------------------------------------------------------------------
__global__ __launch_bounds__(256)
void transpose_bf16(const __bf16* __restrict__ in, __bf16* __restrict__ out,
                    int R, int Cn, long sIn, long sOut)
{
  __shared__ __bf16 t[64][72];
  const __bf16* I = in  + (long)blockIdx.z * sIn;
  __bf16*       O = out + (long)blockIdx.z * sOut;
  const int r0 = blockIdx.y * 64, c0 = blockIdx.x * 64;
  const int tid = threadIdx.x;
  const int lr = tid >> 3, lc = (tid & 7) * 8;
#pragma unroll
  for (int it = 0; it < 2; it++) {
    const int row = lr + it * 32;
    *(bf16x8*)&t[row][lc] = *(const bf16x8*)&I[(long)(r0 + row) * Cn + c0 + lc];
  }
  __syncthreads();
#pragma unroll
  for (int it = 0; it < 2; it++) {
    const int orow = lr + it * 32;      // = column index within tile
    bf16x8 vb;
#pragma unroll
    for (int j = 0; j < 8; j++) vb[j] = t[lc + j][orow];
    *(bf16x8*)&O[(long)(c0 + orow) * R + r0 + lc] = vb;
  }
}

// ---------------------------------------------------------------------------
// Weight transpose + convert: W fp32 [D][D] -> WT bf16 [D][D]; 4 weights via z
// ---------------------------------------------------------------------------
__global__ __launch_bounds__(256)
void wtrans(const float* W0, const float* W1, const float* W2, const float* W3,
            __bf16* O0, __bf16* O1, __bf16* O2, __bf16* O3, int Dd)
{
  __shared__ __bf16 t[64][72];
  const float* W = (blockIdx.z == 0) ? W0 : (blockIdx.z == 1) ? W1 : (blockIdx.z == 2) ? W2 : W3;
  __bf16*      O = (blockIdx.z == 0) ? O0 : (blockIdx.z == 1) ? O1 : (blockIdx.z == 2) ? O2 : O3;
  const int r0 = blockIdx.y * 64, c0 = blockIdx.x * 64;
  const int tid = threadIdx.x;
  const int lr4 = tid >> 4, lc4 = (tid & 15) * 4;
#pragma unroll
  for (int it = 0; it < 4; it++) {
    const int row = lr4 + it * 16;
    float4 v = *(const float4*)&W[(long)(r0 + row) * Dd + c0 + lc4];
    t[row][lc4 + 0] = f2bf(v.x);
    t[row][lc4 + 1] = f2bf(v.y);
    t[row][lc4 + 2] = f2bf(v.z);
    t[row][lc4 + 3] = f2bf(v.w);
  }
  __syncthreads();
  const int lr8 = tid >> 3, lc8 = (tid & 7) * 8;
#pragma unroll
  for (int it = 0; it < 2; it++) {
    const int orow = lr8 + it * 32;
    bf16x8 vb;
#pragma unroll
    for (int j = 0; j < 8; j++) vb[j] = t[lc8 + j][orow];
    *(bf16x8*)&O[(long)(c0 + orow) * Dd + r0 + lc8] = vb;
  }
}

// ---------------------------------------------------------------------------
// k_sum[b*D+d] = sum_s kphiT[(b*D+d)*S + s]   (one block per row)
// ---------------------------------------------------------------------------
__global__ __launch_bounds__(256)
void ksum_k(const __bf16* __restrict__ kphiT, float* __restrict__ ksum, int S)
{
  const long row = blockIdx.x;
  const __bf16* p = kphiT + row * (long)S;
  const int tid = threadIdx.x;
  float s = 0.f;
  for (int j = tid * 8; j < S; j += 256 * 8) {
    bf16x8 v = *(const bf16x8*)&p[j];
#pragma unroll
    for (int e = 0; e < 8; e++) s += (float)v[e];
  }
  __shared__ float red[256];
  red[tid] = s; __syncthreads();
  for (int off = 128; off > 0; off >>= 1) {
    if (tid < off) red[tid] += red[tid + off];
    __syncthreads();
  }
  if (tid == 0) ksum[row] = red[0];
}

// ---------------------------------------------------------------------------
// z[b*S+s] = 1 / (q_phi[row] . k_sum[b] + 1e-6)   (one block per row)
// ---------------------------------------------------------------------------
__global__ __launch_bounds__(256)
void zden_k(const __bf16* __restrict__ qphi, const float* __restrict__ ksum,
            float* __restrict__ z, int Dd, int S)
{
  const long row = blockIdx.x;
  const int  b   = (int)(row / S);
  const __bf16* q = qphi + row * (long)Dd;
  const float* ks = ksum + (long)b * Dd;
  const int tid = threadIdx.x;
  const int i = tid * 4;                      // Dd = 1024 = 256*4 exactly
  bf16x4 qv = *(const bf16x4*)&q[i];
  float4 kv4 = *(const float4*)&ks[i];
  float s = (float)qv[0] * kv4.x + (float)qv[1] * kv4.y +
            (float)qv[2] * kv4.z + (float)qv[3] * kv4.w;
  __shared__ float red[256];
  red[tid] = s; __syncthreads();
  for (int off = 128; off > 0; off >>= 1) {
    if (tid < off) red[tid] += red[tid + off];
    __syncthreads();
  }
  if (tid == 0) z[row] = 1.f / (red[0] + 1e-6f);
}

// ---------------------------------------------------------------------------
extern "C" void kernel_launch(void* const* d_in, const int* in_sizes, int n_in,
                              void* d_out, int out_size, void* d_ws, size_t ws_size,
                              hipStream_t stream)
{
  const float* inputs  = (const float*)d_in[0];
  const float* context = (const float*)d_in[1];
  const float* Wq = (const float*)d_in[2];
  const float* bq = (const float*)d_in[3];
  const float* Wk = (const float*)d_in[4];
  const float* bk = (const float*)d_in[5];
  const float* Wv = (const float*)d_in[6];
  const float* bv = (const float*)d_in[7];
  const float* Wo = (const float*)d_in[8];
  const float* bo = (const float*)d_in[9];
  float* out = (float*)d_out;

  const int Bn = 4, S = 4096, Dd = 1024;
  const long NSD = (long)Bn * S * Dd;          // 16,777,216
  const long MB = 1L << 20;

  char* ws = (char*)d_ws;
  __bf16* xbf   = (__bf16*)(ws + 0 * MB);      // 32 MB; later reused as vT
  __bf16* cbf   = (__bf16*)(ws + 32 * MB);     // 32 MB; later reused as att
  __bf16* qphi  = (__bf16*)(ws + 64 * MB);     // 32 MB
  __bf16* kphi  = (__bf16*)(ws + 96 * MB);     // 32 MB; later reused as kvT
  __bf16* vbuf  = (__bf16*)(ws + 128 * MB);    // 32 MB
  __bf16* kphiT = (__bf16*)(ws + 160 * MB);    // 32 MB
  __bf16* WqT   = (__bf16*)(ws + 192 * MB);    // 2 MB each
  __bf16* WkT   = (__bf16*)(ws + 194 * MB);
  __bf16* WvT   = (__bf16*)(ws + 196 * MB);
  __bf16* WoT   = (__bf16*)(ws + 198 * MB);
  float*  ksum  = (float*)(ws + 200 * MB);     // 16 KB
  float*  zbuf  = (float*)(ws + 201 * MB);     // 64 KB
  __bf16* vT  = xbf;    // xbf dead after q_phi GEMM
  __bf16* att = cbf;    // cbf dead after k/v GEMMs
  __bf16* kvT = kphi;   // kphi dead after its transpose

  // 1) converts
  cvt_f32_bf16<<<16384, 256, 0, stream>>>(inputs,  xbf, NSD);
  cvt_f32_bf16<<<16384, 256, 0, stream>>>(context, cbf, NSD);
  wtrans<<<dim3(16, 16, 4), 256, 0, stream>>>(Wq, Wk, Wv, Wo, WqT, WkT, WvT, WoT, Dd);

  // 2) projections (M=16384, N=1024, K=1024)
  gemm_bt<0><<<dim3(8, 128, 1), 256, 0, stream>>>(xbf, WqT, qphi, Dd, Dd, 0, 0, 0, bq, nullptr, 0, nullptr);
  gemm_bt<0><<<dim3(8, 128, 1), 256, 0, stream>>>(cbf, WkT, kphi, Dd, Dd, 0, 0, 0, bk, nullptr, 0, nullptr);
  gemm_bt<1><<<dim3(8, 128, 1), 256, 0, stream>>>(cbf, WvT, vbuf, Dd, Dd, 0, 0, 0, bv, nullptr, 0, nullptr);

  // 3) transposes to [D][S]
  transpose_bf16<<<dim3(16, 64, 4), 256, 0, stream>>>(kphi, kphiT, S, Dd, (long)S * Dd, (long)S * Dd);
  transpose_bf16<<<dim3(16, 64, 4), 256, 0, stream>>>(vbuf, vT,    S, Dd, (long)S * Dd, (long)S * Dd);

  // 4) k_sum and z
  ksum_k<<<4096, 256, 0, stream>>>(kphiT, ksum, S);
  zden_k<<<16384, 256, 0, stream>>>(qphi, ksum, zbuf, Dd, S);

  // 5) kvT[b][e][d] = sum_s vT[b][e][s] * kphiT[b][d][s]   (M=N=1024, K=4096)
  gemm_bt<2><<<dim3(8, 8, 4), 256, 0, stream>>>(vT, kphiT, kvT, Dd, S,
      (long)Dd * S, (long)Dd * S, (long)Dd * Dd, nullptr, nullptr, 0, nullptr);

  // 6) att[b][s][e] = (sum_d q_phi[b][s][d] * kvT[b][e][d]) * z[b][s]
  gemm_bt<3><<<dim3(8, 32, 4), 256, 0, stream>>>(qphi, kvT, att, Dd, Dd,
      (long)S * Dd, (long)Dd * Dd, (long)S * Dd, nullptr, zbuf, S, nullptr);

  // 7) out = att @ Wo + bo + inputs   (M=16384, K=1024) -> fp32
  gemm_bt<4><<<dim3(8, 128, 1), 256, 0, stream>>>(att, WoT, out, Dd, Dd,
      0, 0, 0, bo, nullptr, 0, inputs);
}

// Round 2
// 642.083 us; speedup vs baseline: 1.0150x; 1.0150x over previous
//
#include <hip/hip_runtime.h>

// ---------------------------------------------------------------------------
// B=4, S=4096, D=1024 linear attention (phi = elu+1), bf16 MFMA GEMMs.
// R2: XCD-aware block swizzle (A-panel stays in one XCD's L2), fused k/v
// projection (N=2048), split-K kv GEMM with fp32 atomic partials.
// ---------------------------------------------------------------------------

typedef __bf16 bf16x8 __attribute__((ext_vector_type(8)));
typedef __bf16 bf16x4 __attribute__((ext_vector_type(4)));
typedef float  f32x4  __attribute__((ext_vector_type(4)));

#define GLOBAL_AS __attribute__((address_space(1)))
#define LDS_AS    __attribute__((address_space(3)))

__device__ __forceinline__ __bf16 f2bf(float f) {
  union { float f; unsigned u; } a; a.f = f;
  unsigned r = a.u + 0x7FFFu + ((a.u >> 16) & 1u);   // RNE (no NaN inputs here)
  union { unsigned short s; __bf16 b; } o; o.s = (unsigned short)(r >> 16);
  return o.b;
}

__device__ __forceinline__ void async_load16(const void* g, void* l) {
  __builtin_amdgcn_global_load_lds((const GLOBAL_AS void*)g, (LDS_AS void*)l, 16, 0, 0);
}

// ---------------------------------------------------------------------------
// GEMM: C[m][n] = sum_k A[m][k] * BT[n][k]
// 128x128 tile, BK=32, 256 threads = 4 waves (2x2), 4x4 16x16x32 MFMAs/wave.
// MODE: 0 = bias+phi->bf16 (q)
//       3 = *z[row]->bf16 (att)
//       4 = bias+residual->f32 (final)
//       5 = split-K (4) fp32 atomicAdd partials (kv)
//       6 = fused k/v: n<1024 -> phi(x+bk)->Cg ; else (x+bv)->Cg2
// ---------------------------------------------------------------------------
template<int MODE>
__global__ __launch_bounds__(256)
void gemm_bt(const __bf16* __restrict__ Ag, const __bf16* __restrict__ Bg,
             void* __restrict__ Cg, void* __restrict__ Cg2,
             int N, int K,
             long sA, long sB, long sC,
             const float* __restrict__ bias, const float* __restrict__ bias2,
             const float* __restrict__ zvec, long sZ,
             const float* __restrict__ resid)
{
  __shared__ __bf16 As[128 * 32];
  __shared__ __bf16 Bs[128 * 32];

  // --- XCD-aware swizzle: linear id % 8 selects the XCD (round-robin).
  // Give XCD j a contiguous band of row-panels (by' in [j*gy/8,(j+1)*gy/8)),
  // sweeping all bx for one by before advancing: A-panel read by exactly one
  // XCD and reused from its L2; B stays L2-resident.
  int bx = blockIdx.x, by = blockIdx.y;
  {
    const int gx = gridDim.x, gy = gridDim.y;
    if ((gy & 7) == 0) {
      const int f = by * gx + bx;
      const int j = f & 7;
      const int u = f >> 3;
      bx = u % gx;
      by = j * (gy >> 3) + u / gx;
    }
  }
  int bz = blockIdx.z;
  int k0beg = 0, k0end = K;
  if (MODE == 5) {               // z = batch*4 + split
    const int split = bz & 3;
    bz >>= 2;
    k0beg = split * (K >> 2);
    k0end = k0beg + (K >> 2);
  }

  const int tid = threadIdx.x;
  const __bf16* A = Ag + (long)by * 128 * K + bz * sA;
  const __bf16* B = Bg + (long)bx * 128 * K + bz * sB;

  // staging: thread t covers 16B; row = t/4 (+64 chunk 1), col = (t%4)*8
  const int sr = tid >> 2;
  const int sc = (tid & 3) * 8;

  const int lane = tid & 63;
  const int wave = tid >> 6;
  const int wm   = (wave >> 1) * 64;
  const int wn   = (wave & 1) * 64;
  const int ln   = lane & 15;
  const int quad = lane >> 4;

  f32x4 acc[4][4];
  const f32x4 zero = {0.f, 0.f, 0.f, 0.f};
#pragma unroll
  for (int i = 0; i < 4; i++)
#pragma unroll
    for (int j = 0; j < 4; j++) acc[i][j] = zero;

  for (int k0 = k0beg; k0 < k0end; k0 += 32) {
    async_load16(A + (long)sr * K        + k0 + sc, As + tid * 8);
    async_load16(A + (long)(sr + 64) * K + k0 + sc, As + 2048 + tid * 8);
    async_load16(B + (long)sr * K        + k0 + sc, Bs + tid * 8);
    async_load16(B + (long)(sr + 64) * K + k0 + sc, Bs + 2048 + tid * 8);
    __syncthreads();

    bf16x8 af[4], bfr[4];
#pragma unroll
    for (int i = 0; i < 4; i++)
      af[i] = *(const bf16x8*)(As + (wm + i * 16 + ln) * 32 + quad * 8);
#pragma unroll
    for (int j = 0; j < 4; j++)
      bfr[j] = *(const bf16x8*)(Bs + (wn + j * 16 + ln) * 32 + quad * 8);
#pragma unroll
    for (int i = 0; i < 4; i++)
#pragma unroll
      for (int j = 0; j < 4; j++)
        acc[i][j] = __builtin_amdgcn_mfma_f32_16x16x32_bf16(af[i], bfr[j], acc[i][j], 0, 0, 0);
    __syncthreads();
  }

  // epilogue: C/D layout col = lane&15, row = quad*4 + reg (m89-verified)
  const long m0  = (long)by * 128;
  const int  n0g = bx * 128;
#pragma unroll
  for (int i = 0; i < 4; i++) {
#pragma unroll
    for (int j = 0; j < 4; j++) {
#pragma unroll
      for (int r = 0; r < 4; r++) {
        const int lrow = wm + i * 16 + quad * 4 + r;
        const int lcol = wn + j * 16 + ln;
        const long gm  = m0 + lrow;
        const int  gn  = n0g + lcol;
        float x = acc[i][j][r];
        if (MODE == 0) {
          x += bias[gn];
          x = (x > 0.f) ? (x + 1.f) : __expf(x);
          ((__bf16*)Cg)[(long)bz * sC + gm * (long)N + gn] = f2bf(x);
        } else if (MODE == 3) {
          x *= zvec[(long)bz * sZ + gm];
          ((__bf16*)Cg)[(long)bz * sC + gm * (long)N + gn] = f2bf(x);
        } else if (MODE == 4) {
          x += bias[gn];
          ((float*)Cg)[gm * (long)N + gn] = x + resid[gm * (long)N + gn];
        } else if (MODE == 5) {
          __hip_atomic_fetch_add(&((float*)Cg)[(long)bz * sC + gm * (long)N + gn],
                                 x, __ATOMIC_RELAXED, __HIP_MEMORY_SCOPE_AGENT);
        } else if (MODE == 6) {
          if (gn < 1024) {
            x += bias[gn];
            x = (x > 0.f) ? (x + 1.f) : __expf(x);
            ((__bf16*)Cg)[gm * 1024L + gn] = f2bf(x);
          } else {
            x += bias2[gn - 1024];
            ((__bf16*)Cg2)[gm * 1024L + (gn - 1024)] = f2bf(x);
          }
        }
      }
    }
  }
}

// ---------------------------------------------------------------------------
__global__ __launch_bounds__(256)
void cvt_f32_bf16(const float* __restrict__ x, __bf16* __restrict__ y, long n)
{
  long i = ((long)blockIdx.x * 256 + threadIdx.x) * 4;
  if (i < n) {
    float4 v = *(const float4*)(x + i);
    bf16x4 o;
    o[0] = f2bf(v.x); o[1] = f2bf(v.y); o[2] = f2bf(v.z); o[3] = f2bf(v.w);
    *(bf16x4*)(y + i) = o;
  }
}

// ---------------------------------------------------------------------------
// bf16 [R][Cn] -> [Cn][R] transpose, 64x64 LDS tiles, batched (blockIdx.z)
// ---------------------------------------------------------------------------
__global__ __launch_bounds__(256)
void transpose_bf16(const __bf16* __restrict__ in, __bf16* __restrict__ out,
                    int R, int Cn, long sIn, long sOut)
{
  __shared__ __bf16 t[64][72];
  const __bf16* I = in  + (long)blockIdx.z * sIn;
  __bf16*       O = out + (long)blockIdx.z * sOut;
  const int r0 = blockIdx.y * 64, c0 = blockIdx.x * 64;
  const int tid = threadIdx.x;
  const int lr = tid >> 3, lc = (tid & 7) * 8;
#pragma unroll
  for (int it = 0; it < 2; it++) {
    const int row = lr + it * 32;
    *(bf16x8*)&t[row][lc] = *(const bf16x8*)&I[(long)(r0 + row) * Cn + c0 + lc];
  }
  __syncthreads();
#pragma unroll
  for (int it = 0; it < 2; it++) {
    const int orow = lr + it * 32;
    bf16x8 vb;
#pragma unroll
    for (int j = 0; j < 8; j++) vb[j] = t[lc + j][orow];
    *(bf16x8*)&O[(long)(c0 + orow) * R + r0 + lc] = vb;
  }
}

// ---------------------------------------------------------------------------
// Weight transpose + convert: W fp32 [D][D] -> WT bf16 [D][D]; 4 weights via z
// ---------------------------------------------------------------------------
__global__ __launch_bounds__(256)
void wtrans(const float* W0, const float* W1, const float* W2, const float* W3,
            __bf16* O0, __bf16* O1, __bf16* O2, __bf16* O3, int Dd)
{
  __shared__ __bf16 t[64][72];
  const float* W = (blockIdx.z == 0) ? W0 : (blockIdx.z == 1) ? W1 : (blockIdx.z == 2) ? W2 : W3;
  __bf16*      O = (blockIdx.z == 0) ? O0 : (blockIdx.z == 1) ? O1 : (blockIdx.z == 2) ? O2 : O3;
  const int r0 = blockIdx.y * 64, c0 = blockIdx.x * 64;
  const int tid = threadIdx.x;
  const int lr4 = tid >> 4, lc4 = (tid & 15) * 4;
#pragma unroll
  for (int it = 0; it < 4; it++) {
    const int row = lr4 + it * 16;
    float4 v = *(const float4*)&W[(long)(r0 + row) * Dd + c0 + lc4];
    t[row][lc4 + 0] = f2bf(v.x);
    t[row][lc4 + 1] = f2bf(v.y);
    t[row][lc4 + 2] = f2bf(v.z);
    t[row][lc4 + 3] = f2bf(v.w);
  }
  __syncthreads();
  const int lr8 = tid >> 3, lc8 = (tid & 7) * 8;
#pragma unroll
  for (int it = 0; it < 2; it++) {
    const int orow = lr8 + it * 32;
    bf16x8 vb;
#pragma unroll
    for (int j = 0; j < 8; j++) vb[j] = t[lc8 + j][orow];
    *(bf16x8*)&O[(long)(c0 + orow) * Dd + r0 + lc8] = vb;
  }
}

// ---------------------------------------------------------------------------
// k_sum[b*D+d] = sum_s kphiT[(b*D+d)*S + s]
// ---------------------------------------------------------------------------
__global__ __launch_bounds__(256)
void ksum_k(const __bf16* __restrict__ kphiT, float* __restrict__ ksum, int S)
{
  const long row = blockIdx.x;
  const __bf16* p = kphiT + row * (long)S;
  const int tid = threadIdx.x;
  float s = 0.f;
  for (int j = tid * 8; j < S; j += 256 * 8) {
    bf16x8 v = *(const bf16x8*)&p[j];
#pragma unroll
    for (int e = 0; e < 8; e++) s += (float)v[e];
  }
  __shared__ float red[256];
  red[tid] = s; __syncthreads();
  for (int off = 128; off > 0; off >>= 1) {
    if (tid < off) red[tid] += red[tid + off];
    __syncthreads();
  }
  if (tid == 0) ksum[row] = red[0];
}

// ---------------------------------------------------------------------------
// z[b*S+s] = 1 / (q_phi[row] . k_sum[b] + 1e-6)
// ---------------------------------------------------------------------------
__global__ __launch_bounds__(256)
void zden_k(const __bf16* __restrict__ qphi, const float* __restrict__ ksum,
            float* __restrict__ z, int Dd, int S)
{
  const long row = blockIdx.x;
  const int  b   = (int)(row / S);
  const __bf16* q = qphi + row * (long)Dd;
  const float* ks = ksum + (long)b * Dd;
  const int tid = threadIdx.x;
  const int i = tid * 4;                      // Dd = 1024 = 256*4 exactly
  bf16x4 qv = *(const bf16x4*)&q[i];
  float4 kv4 = *(const float4*)&ks[i];
  float s = (float)qv[0] * kv4.x + (float)qv[1] * kv4.y +
            (float)qv[2] * kv4.z + (float)qv[3] * kv4.w;
  __shared__ float red[256];
  red[tid] = s; __syncthreads();
  for (int off = 128; off > 0; off >>= 1) {
    if (tid < off) red[tid] += red[tid + off];
    __syncthreads();
  }
  if (tid == 0) z[row] = 1.f / (red[0] + 1e-6f);
}

// ---------------------------------------------------------------------------
extern "C" void kernel_launch(void* const* d_in, const int* in_sizes, int n_in,
                              void* d_out, int out_size, void* d_ws, size_t ws_size,
                              hipStream_t stream)
{
  const float* inputs  = (const float*)d_in[0];
  const float* context = (const float*)d_in[1];
  const float* Wq = (const float*)d_in[2];
  const float* bq = (const float*)d_in[3];
  const float* Wk = (const float*)d_in[4];
  const float* bk = (const float*)d_in[5];
  const float* Wv = (const float*)d_in[6];
  const float* bv = (const float*)d_in[7];
  const float* Wo = (const float*)d_in[8];
  const float* bo = (const float*)d_in[9];
  float* out = (float*)d_out;

  const int Bn = 4, S = 4096, Dd = 1024;
  const long NSD = (long)Bn * S * Dd;          // 16,777,216
  const long MB = 1L << 20;

  char* ws = (char*)d_ws;
  __bf16* xbf   = (__bf16*)(ws + 0 * MB);      // 32 MB; reused as vT
  __bf16* cbf   = (__bf16*)(ws + 32 * MB);     // 32 MB; reused as att
  __bf16* qphi  = (__bf16*)(ws + 64 * MB);     // 32 MB
  __bf16* kphi  = (__bf16*)(ws + 96 * MB);     // 32 MB; reused as kvT (8 MB)
  __bf16* vbuf  = (__bf16*)(ws + 128 * MB);    // 32 MB; reused as kvf (16 MB fp32)
  __bf16* kphiT = (__bf16*)(ws + 160 * MB);    // 32 MB
  __bf16* WqT   = (__bf16*)(ws + 192 * MB);    // 2 MB each; WkT/WvT contiguous!
  __bf16* WkT   = (__bf16*)(ws + 194 * MB);
  __bf16* WvT   = (__bf16*)(ws + 196 * MB);
  __bf16* WoT   = (__bf16*)(ws + 198 * MB);
  float*  ksum  = (float*)(ws + 200 * MB);
  float*  zbuf  = (float*)(ws + 201 * MB);
  __bf16* vT  = xbf;    // xbf dead after q GEMM
  __bf16* att = cbf;    // cbf dead after fused k/v GEMM
  __bf16* kvT = kphi;   // kphi dead after its transpose
  float*  kvf = (float*)vbuf;   // vbuf dead after its transpose

  // 1) converts
  cvt_f32_bf16<<<16384, 256, 0, stream>>>(inputs,  xbf, NSD);
  cvt_f32_bf16<<<16384, 256, 0, stream>>>(context, cbf, NSD);
  wtrans<<<dim3(16, 16, 4), 256, 0, stream>>>(Wq, Wk, Wv, Wo, WqT, WkT, WvT, WoT, Dd);

  // 2) projections: q (N=1024); fused k/v (N=2048, WkT||WvT contiguous)
  gemm_bt<0><<<dim3(8, 128, 1), 256, 0, stream>>>(xbf, WqT, qphi, nullptr,
      Dd, Dd, 0, 0, 0, bq, nullptr, nullptr, 0, nullptr);
  gemm_bt<6><<<dim3(16, 128, 1), 256, 0, stream>>>(cbf, WkT, kphi, vbuf,
      2048, Dd, 0, 0, 0, bk, bv, nullptr, 0, nullptr);

  // 3) transposes to [D][S]
  transpose_bf16<<<dim3(16, 64, 4), 256, 0, stream>>>(kphi, kphiT, S, Dd, (long)S * Dd, (long)S * Dd);
  transpose_bf16<<<dim3(16, 64, 4), 256, 0, stream>>>(vbuf, vT,    S, Dd, (long)S * Dd, (long)S * Dd);

  // 4) k_sum and z
  ksum_k<<<4096, 256, 0, stream>>>(kphiT, ksum, S);
  zden_k<<<16384, 256, 0, stream>>>(qphi, ksum, zbuf, Dd, S);

  // 5) kv split-K(4): kvf[b][e][d] += partial; z = batch*4 + split
  hipMemsetAsync(kvf, 0, (size_t)Bn * Dd * Dd * sizeof(float), stream);
  gemm_bt<5><<<dim3(8, 8, 16), 256, 0, stream>>>(vT, kphiT, kvf, nullptr,
      Dd, S, (long)Dd * S, (long)Dd * S, (long)Dd * Dd, nullptr, nullptr, nullptr, 0, nullptr);
  cvt_f32_bf16<<<4096, 256, 0, stream>>>(kvf, kvT, (long)Bn * Dd * Dd);

  // 6) att[b][s][e] = (sum_d qphi[b][s][d] * kvT[b][e][d]) * z[b][s]
  gemm_bt<3><<<dim3(8, 32, 4), 256, 0, stream>>>(qphi, kvT, att, nullptr,
      Dd, Dd, (long)S * Dd, (long)Dd * Dd, (long)S * Dd, nullptr, nullptr, zbuf, S, nullptr);

  // 7) out = att @ Wo + bo + inputs -> fp32
  gemm_bt<4><<<dim3(8, 128, 1), 256, 0, stream>>>(att, WoT, out, nullptr,
      Dd, Dd, 0, 0, 0, bo, nullptr, nullptr, 0, inputs);
}

// Round 3
// 522.994 us; speedup vs baseline: 1.2461x; 1.2277x over previous
//
#include <hip/hip_runtime.h>

// ---------------------------------------------------------------------------
// B=4, S=4096, D=1024 linear attention (phi = elu+1), bf16 MFMA GEMMs.
// R3: BK=64 K-loop + XOR-swizzled LDS (conflict-free ds_read_b128),
//     algebraic reorder out = z*(q @ (kv@Wo)) (kills the att GEMM),
//     k/v GEMM writes kphiT/vT directly via LDS-transposed epilogue.
// ---------------------------------------------------------------------------

typedef __bf16 bf16x8 __attribute__((ext_vector_type(8)));
typedef __bf16 bf16x4 __attribute__((ext_vector_type(4)));
typedef float  f32x4  __attribute__((ext_vector_type(4)));

#define GLOBAL_AS __attribute__((address_space(1)))
#define LDS_AS    __attribute__((address_space(3)))

#define SS 4096
#define DD 1024

__device__ __forceinline__ __bf16 f2bf(float f) {
  union { float f; unsigned u; } a; a.f = f;
  unsigned r = a.u + 0x7FFFu + ((a.u >> 16) & 1u);   // RNE (no NaN inputs here)
  union { unsigned short s; __bf16 b; } o; o.s = (unsigned short)(r >> 16);
  return o.b;
}

__device__ __forceinline__ void async_load16(const void* g, void* l) {
  __builtin_amdgcn_global_load_lds((const GLOBAL_AS void*)g, (LDS_AS void*)l, 16, 0, 0);
}

// ---------------------------------------------------------------------------
// GEMM: C[m][n] = sum_k A[m][k] * BT[n][k]
// 128x128 tile, BK=64, 256 threads = 4 waves (2x2), 2x16 16x16x32 MFMAs/wave.
// LDS XOR swizzle: LDS[row][chunk c] holds global 8-elem chunk c^(row&7);
// reads at chunk (ksub*4+quad)^(ln&7) -> 2 lanes/bank (free, m136).
// MODE: 0 = bias+phi->bf16 row-major (q)
//       5 = split-K(4) fp32 atomicAdd partials (kv)
//       6 = fused k/v, TRANSPOSED dual output -> kphiT/vT [b][D][S]
//       7 = plain->bf16 (M2 = kv@Wo, stored as M2T[f][d])
//       8 = z*acc + bias + residual -> f32 (final; B operand per-batch)
// ---------------------------------------------------------------------------
template<int MODE>
__global__ __launch_bounds__(256)
void gemm_bt(const __bf16* __restrict__ Ag, const __bf16* __restrict__ Bg,
             void* __restrict__ Cg, void* __restrict__ Cg2,
             int N, int K, long sA, long sB, long sC,
             const float* __restrict__ bias, const float* __restrict__ bias2,
             const float* __restrict__ zvec,
             const float* __restrict__ resid)
{
  union SMem {
    struct { __bf16 As[128 * 64]; __bf16 Bs[128 * 64]; } s;  // 32 KB
    __bf16 T[128 * 136];                                     // 34 KB (epilogue)
  };
  __shared__ SMem sm;

  // XCD-aware swizzle (linear id % 8 = XCD): XCD j owns a contiguous band of
  // row-panels, sweeping all bx of one by before advancing.
  int bx = blockIdx.x, by = blockIdx.y;
  {
    const int gx = gridDim.x, gy = gridDim.y;
    if ((gy & 7) == 0) {
      const int f = by * gx + bx;
      const int j = f & 7;
      const int u = f >> 3;
      bx = u % gx;
      by = j * (gy >> 3) + u / gx;
    }
  }
  int bz = blockIdx.z;
  int k0beg = 0, k0end = K;
  if (MODE == 5) {               // z = batch*4 + split
    const int split = bz & 3;
    bz >>= 2;
    k0beg = split * (K >> 2);
    k0end = k0beg + (K >> 2);
  }

  const int tid = threadIdx.x;
  const long m0 = (long)by * 128;
  const __bf16* A = Ag + m0 * K + bz * sA;
  const __bf16* B;
  if (MODE == 8) {
    const int b = (int)(m0 >> 12);           // batch = m0 / S
    B = Bg + (long)bx * 128 * K + (long)b * sB;
  } else {
    B = Bg + (long)bx * 128 * K + bz * sB;
  }

  // staging: thread t covers 16B; pass p covers rows p*32..p*32+31
  const int srow = tid >> 3;                   // 0..31
  const int gcc8 = ((tid & 7) ^ (srow & 7)) * 8;  // XOR-swizzled global chunk

  const int lane = tid & 63;
  const int wave = tid >> 6;
  const int wm   = (wave >> 1) * 64;
  const int wn   = (wave & 1) * 64;
  const int ln   = lane & 15;
  const int quad = lane >> 4;
  const int rk   = ln & 7;

  f32x4 acc[4][4];
  const f32x4 zero = {0.f, 0.f, 0.f, 0.f};
#pragma unroll
  for (int i = 0; i < 4; i++)
#pragma unroll
    for (int j = 0; j < 4; j++) acc[i][j] = zero;

  for (int k0 = k0beg; k0 < k0end; k0 += 64) {
#pragma unroll
    for (int p = 0; p < 4; p++) {
      async_load16(A + (long)(p * 32 + srow) * K + k0 + gcc8, sm.s.As + p * 2048 + tid * 8);
      async_load16(B + (long)(p * 32 + srow) * K + k0 + gcc8, sm.s.Bs + p * 2048 + tid * 8);
    }
    __syncthreads();

#pragma unroll
    for (int ksub = 0; ksub < 2; ksub++) {
      const int cc = (ksub * 4 + quad) ^ rk;   // LDS chunk holding wanted k-chunk
      bf16x8 af[4], bfr[4];
#pragma unroll
      for (int i = 0; i < 4; i++)
        af[i] = *(const bf16x8*)(sm.s.As + (wm + i * 16 + ln) * 64 + cc * 8);
#pragma unroll
      for (int j = 0; j < 4; j++)
        bfr[j] = *(const bf16x8*)(sm.s.Bs + (wn + j * 16 + ln) * 64 + cc * 8);
#pragma unroll
      for (int i = 0; i < 4; i++)
#pragma unroll
        for (int j = 0; j < 4; j++)
          acc[i][j] = __builtin_amdgcn_mfma_f32_16x16x32_bf16(af[i], bfr[j], acc[i][j], 0, 0, 0);
    }
    __syncthreads();
  }

  // epilogue: C/D layout col = lane&15, row = quad*4 + reg (m89-verified)
  const int n0g = bx * 128;

  if (MODE == 6) {
    // fused k/v with transposed store: tile -> LDS [n][s] -> coalesced [d][s]
    const bool isK = (n0g < 1024);
    const float* bb = isK ? bias : bias2;
    const int nb = isK ? n0g : (n0g - 1024);
#pragma unroll
    for (int i = 0; i < 4; i++)
#pragma unroll
      for (int j = 0; j < 4; j++)
#pragma unroll
        for (int r = 0; r < 4; r++) {
          const int s_loc = wm + i * 16 + quad * 4 + r;
          const int n_loc = wn + j * 16 + ln;
          float x = acc[i][j][r] + bb[nb + n_loc];
          if (isK) x = (x > 0.f) ? (x + 1.f) : __expf(x);
          sm.T[n_loc * 136 + s_loc] = f2bf(x);
        }
    __syncthreads();
    const int  b    = (int)(m0 >> 12);
    const long s_in = m0 & 4095;
    __bf16* dst = (__bf16*)(isK ? Cg : Cg2) + (long)b * DD * SS;
#pragma unroll
    for (int pass = 0; pass < 8; pass++) {
      const int row = (tid >> 4) + pass * 16;  // n_loc (= d within tile)
      const int c   = (tid & 15) * 8;          // s chunk
      bf16x8 vv = *(const bf16x8*)(sm.T + row * 136 + c);
      *(bf16x8*)&dst[(long)(nb + row) * SS + s_in + c] = vv;
    }
    return;
  }

#pragma unroll
  for (int i = 0; i < 4; i++) {
#pragma unroll
    for (int j = 0; j < 4; j++) {
#pragma unroll
      for (int r = 0; r < 4; r++) {
        const int lrow = wm + i * 16 + quad * 4 + r;
        const int lcol = wn + j * 16 + ln;
        const long gm  = m0 + lrow;
        const int  gn  = n0g + lcol;
        float x = acc[i][j][r];
        if (MODE == 0) {
          x += bias[gn];
          x = (x > 0.f) ? (x + 1.f) : __expf(x);
          ((__bf16*)Cg)[gm * (long)N + gn] = f2bf(x);
        } else if (MODE == 5) {
          __hip_atomic_fetch_add(&((float*)Cg)[(long)bz * sC + gm * (long)N + gn],
                                 x, __ATOMIC_RELAXED, __HIP_MEMORY_SCOPE_AGENT);
        } else if (MODE == 7) {
          ((__bf16*)Cg)[(long)bz * sC + gm * (long)N + gn] = f2bf(x);
        } else if (MODE == 8) {
          x = x * zvec[gm] + bias[gn];
          ((float*)Cg)[gm * (long)N + gn] = x + resid[gm * (long)N + gn];
        }
      }
    }
  }
}

// ---------------------------------------------------------------------------
__global__ __launch_bounds__(256)
void cvt_f32_bf16(const float* __restrict__ x, __bf16* __restrict__ y, long n)
{
  long i = ((long)blockIdx.x * 256 + threadIdx.x) * 4;
  if (i < n) {
    float4 v = *(const float4*)(x + i);
    bf16x4 o;
    o[0] = f2bf(v.x); o[1] = f2bf(v.y); o[2] = f2bf(v.z); o[3] = f2bf(v.w);
    *(bf16x4*)(y + i) = o;
  }
}

// ---------------------------------------------------------------------------
// Weight transpose + convert: W fp32 [D][D] -> WT bf16 [D][D]; 4 weights via z
// ---------------------------------------------------------------------------
__global__ __launch_bounds__(256)
void wtrans(const float* W0, const float* W1, const float* W2, const float* W3,
            __bf16* O0, __bf16* O1, __bf16* O2, __bf16* O3, int Dd)
{
  __shared__ __bf16 t[64][72];
  const float* W = (blockIdx.z == 0) ? W0 : (blockIdx.z == 1) ? W1 : (blockIdx.z == 2) ? W2 : W3;
  __bf16*      O = (blockIdx.z == 0) ? O0 : (blockIdx.z == 1) ? O1 : (blockIdx.z == 2) ? O2 : O3;
  const int r0 = blockIdx.y * 64, c0 = blockIdx.x * 64;
  const int tid = threadIdx.x;
  const int lr4 = tid >> 4, lc4 = (tid & 15) * 4;
#pragma unroll
  for (int it = 0; it < 4; it++) {
    const int row = lr4 + it * 16;
    float4 v = *(const float4*)&W[(long)(r0 + row) * Dd + c0 + lc4];
    t[row][lc4 + 0] = f2bf(v.x);
    t[row][lc4 + 1] = f2bf(v.y);
    t[row][lc4 + 2] = f2bf(v.z);
    t[row][lc4 + 3] = f2bf(v.w);
  }
  __syncthreads();
  const int lr8 = tid >> 3, lc8 = (tid & 7) * 8;
#pragma unroll
  for (int it = 0; it < 2; it++) {
    const int orow = lr8 + it * 32;
    bf16x8 vb;
#pragma unroll
    for (int j = 0; j < 8; j++) vb[j] = t[lc8 + j][orow];
    *(bf16x8*)&O[(long)(c0 + orow) * Dd + r0 + lc8] = vb;
  }
}

// ---------------------------------------------------------------------------
// k_sum[b*D+d] = sum_s kphiT[(b*D+d)*S + s]
// ---------------------------------------------------------------------------
__global__ __launch_bounds__(256)
void ksum_k(const __bf16* __restrict__ kphiT, float* __restrict__ ksum, int S)
{
  const long row = blockIdx.x;
  const __bf16* p = kphiT + row * (long)S;
  const int tid = threadIdx.x;
  float s = 0.f;
  for (int j = tid * 8; j < S; j += 256 * 8) {
    bf16x8 v = *(const bf16x8*)&p[j];
#pragma unroll
    for (int e = 0; e < 8; e++) s += (float)v[e];
  }
  __shared__ float red[256];
  red[tid] = s; __syncthreads();
  for (int off = 128; off > 0; off >>= 1) {
    if (tid < off) red[tid] += red[tid + off];
    __syncthreads();
  }
  if (tid == 0) ksum[row] = red[0];
}

// ---------------------------------------------------------------------------
// z[b*S+s] = 1 / (q_phi[row] . k_sum[b] + 1e-6)
// ---------------------------------------------------------------------------
__global__ __launch_bounds__(256)
void zden_k(const __bf16* __restrict__ qphi, const float* __restrict__ ksum,
            float* __restrict__ z, int Dd, int S)
{
  const long row = blockIdx.x;
  const int  b   = (int)(row / S);
  const __bf16* q = qphi + row * (long)Dd;
  const float* ks = ksum + (long)b * Dd;
  const int tid = threadIdx.x;
  const int i = tid * 4;                      // Dd = 1024 = 256*4 exactly
  bf16x4 qv = *(const bf16x4*)&q[i];
  float4 kv4 = *(const float4*)&ks[i];
  float s = (float)qv[0] * kv4.x + (float)qv[1] * kv4.y +
            (float)qv[2] * kv4.z + (float)qv[3] * kv4.w;
  __shared__ float red[256];
  red[tid] = s; __syncthreads();
  for (int off = 128; off > 0; off >>= 1) {
    if (tid < off) red[tid] += red[tid + off];
    __syncthreads();
  }
  if (tid == 0) z[row] = 1.f / (red[0] + 1e-6f);
}

// ---------------------------------------------------------------------------
extern "C" void kernel_launch(void* const* d_in, const int* in_sizes, int n_in,
                              void* d_out, int out_size, void* d_ws, size_t ws_size,
                              hipStream_t stream)
{
  const float* inputs  = (const float*)d_in[0];
  const float* context = (const float*)d_in[1];
  const float* Wq = (const float*)d_in[2];
  const float* bq = (const float*)d_in[3];
  const float* Wk = (const float*)d_in[4];
  const float* bk = (const float*)d_in[5];
  const float* Wv = (const float*)d_in[6];
  const float* bv = (const float*)d_in[7];
  const float* Wo = (const float*)d_in[8];
  const float* bo = (const float*)d_in[9];
  float* out = (float*)d_out;

  const int Bn = 4;
  const long NSD = (long)Bn * SS * DD;         // 16,777,216
  const long MB = 1L << 20;

  char* ws = (char*)d_ws;
  __bf16* xbf   = (__bf16*)(ws + 0 * MB);      // 32 MB
  __bf16* cbf   = (__bf16*)(ws + 32 * MB);     // 32 MB
  __bf16* qphi  = (__bf16*)(ws + 64 * MB);     // 32 MB
  __bf16* kphiT = (__bf16*)(ws + 96 * MB);     // 32 MB   [b][D][S]
  __bf16* vT    = (__bf16*)(ws + 128 * MB);    // 32 MB   [b][D][S]
  float*  kvf   = (float*)(ws + 160 * MB);     // 16 MB   [b][D][D] fp32
  __bf16* kvbf  = (__bf16*)(ws + 176 * MB);    // 8 MB    [b][D][D]
  __bf16* M2T   = (__bf16*)(ws + 184 * MB);    // 8 MB    [b][D][D]  (kv@Wo)^T
  __bf16* WqT   = (__bf16*)(ws + 192 * MB);    // 2 MB each; WkT/WvT contiguous!
  __bf16* WkT   = (__bf16*)(ws + 194 * MB);
  __bf16* WvT   = (__bf16*)(ws + 196 * MB);
  __bf16* WoT   = (__bf16*)(ws + 198 * MB);
  float*  ksum  = (float*)(ws + 200 * MB);
  float*  zbuf  = (float*)(ws + 201 * MB);

  // 1) converts
  cvt_f32_bf16<<<16384, 256, 0, stream>>>(inputs,  xbf, NSD);
  cvt_f32_bf16<<<16384, 256, 0, stream>>>(context, cbf, NSD);
  wtrans<<<dim3(16, 16, 4), 256, 0, stream>>>(Wq, Wk, Wv, Wo, WqT, WkT, WvT, WoT, DD);

  // 2) q projection: qphi = phi(x Wq + bq), row-major [B*S][D]
  gemm_bt<0><<<dim3(8, 128, 1), 256, 0, stream>>>(xbf, WqT, qphi, nullptr,
      DD, DD, 0, 0, 0, bq, nullptr, nullptr, nullptr);

  // 3) fused k/v projection (N=2048, WkT||WvT contiguous), transposed outputs
  gemm_bt<6><<<dim3(16, 128, 1), 256, 0, stream>>>(cbf, WkT, kphiT, vT,
      2048, DD, 0, 0, 0, bk, bv, nullptr, nullptr);

  // 4) k_sum and z
  ksum_k<<<4096, 256, 0, stream>>>(kphiT, ksum, SS);
  zden_k<<<16384, 256, 0, stream>>>(qphi, ksum, zbuf, DD, SS);

  // 5) kv[b][d][e] = sum_s kphiT[b][d][s] * vT[b][e][s], split-K(4) fp32 atomics
  hipMemsetAsync(kvf, 0, (size_t)Bn * DD * DD * sizeof(float), stream);
  gemm_bt<5><<<dim3(8, 8, 16), 256, 0, stream>>>(kphiT, vT, kvf, nullptr,
      DD, SS, (long)DD * SS, (long)DD * SS, (long)DD * DD,
      nullptr, nullptr, nullptr, nullptr);
  cvt_f32_bf16<<<4096, 256, 0, stream>>>(kvf, kvbf, (long)Bn * DD * DD);

  // 6) M2T[b][f][d] = sum_e WoT[f][e] * kv[b][d][e]   (tiny: 8.6 GF)
  gemm_bt<7><<<dim3(8, 8, 4), 256, 0, stream>>>(WoT, kvbf, M2T, nullptr,
      DD, DD, 0, (long)DD * DD, (long)DD * DD, nullptr, nullptr, nullptr, nullptr);

  // 7) out[s][f] = z[s] * (sum_d qphi[s][d] * M2T[b][f][d]) + bo[f] + x[s][f]
  gemm_bt<8><<<dim3(8, 128, 1), 256, 0, stream>>>(qphi, M2T, out, nullptr,
      DD, DD, 0, (long)DD * DD, 0, bo, nullptr, zbuf, inputs);
}